// Round 6
// baseline (2061.921 us; speedup 1.0000x reference)
//
#include <hip/hip_runtime.h>
#include <cstddef>

// BasicRNN, Round 9.
// Phase A: X = obs @ W_in^T + b_in + b_h  -> hs region   [split-bf16 MFMA GEMM]
// Phase B: recurrence — R6 protocol, R9 poll scheduling (see below).
// Phase C: outs = hs @ W_out^T + b_out                   [plain bf16 MFMA GEMM]
//
// R9 change (rnn only): 2-deep software-pipelined poll using ONLY
// compiler-visible __hip_atomic_load batches (A/B ping-pong over the same 4
// words). The compiler's waitcnt pass emits counted vmcnt (B outstanding
// while checking A) -> sampling period ~L/2 vs R6's ~L per word. Unlike R7
// (inline-asm loads, invisible to the waitcnt pass -> register corruption),
// every wait here is compiler-derived and sound; worst case = R6 perf.
// Protocol (stores, tags, slabs) byte-identical to R6. Hang-free: same exit
// condition, same publish primitive. __launch_bounds__(512,1): 128 blocks on
// 256 CUs never co-locate 2/CU, so the old (512,2) VGPR cap was pure loss.

static constexpr int Bb = 64;
static constexpr int Tt = 512;
static constexpr int Dd = 256;
static constexpr int Hh = 1024;
static constexpr int Oo = 256;

typedef __attribute__((ext_vector_type(8))) short bf16x8;
typedef __attribute__((ext_vector_type(4))) float f32x4;
typedef unsigned long long ull;

static __device__ __forceinline__ unsigned short f2b(float f) {
    unsigned int u = __float_as_uint(f);
    u = (u + 0x7fffu + ((u >> 16) & 1u)) >> 16;
    return (unsigned short)u;
}
static __device__ __forceinline__ float b2f(unsigned short b) {
    return __uint_as_float(((unsigned int)b) << 16);
}
static __device__ __forceinline__ ull pack4(float a, float b, float c, float d) {
    return (ull)f2b(a) | ((ull)f2b(b) << 16) | ((ull)f2b(c) << 32) | ((ull)f2b(d) << 48);
}

// Fragment-major LDS layout for h (row r 0..1023, batch m 0..3) — rnn only.
static __device__ __forceinline__ int hla_base(int r) {
    return ((r >> 5) << 7) + (((r >> 3) & 3) << 3) + (r & 7);
}
static __device__ __forceinline__ int hla_addr(int r, int m) {
    return hla_base(r) + (m << 5);
}

// ---------------------------------------------------------------- MFMA GEMM
// (unchanged from round 8 — passed, absmax 0.03125)
// C[m,n] = sum_k A[m,k]*Bt[n,k] + bias1[n] (+bias2[n]).
// Tiles: BM=BN=128, BK=32. 256 threads = 4 waves; wave quadrant 64x64 =
// 4x4 frags of 16x16x32. LDS row stride 40 shorts. SPLIT=1: Markidis split.
template <int SPLIT>
__global__ __launch_bounds__(256) void gemm_mfma_bt(const float* __restrict__ A,
                                                    const float* __restrict__ Bt,
                                                    const float* __restrict__ bias1,
                                                    const float* __restrict__ bias2,
                                                    float* __restrict__ C,
                                                    int M, int N, int K)
{
    __shared__ short Ah[128 * 40];
    __shared__ short Bh[128 * 40];
    __shared__ short Al[SPLIT ? 128 * 40 : 8];
    __shared__ short Bl[SPLIT ? 128 * 40 : 8];

    const int tid = threadIdx.x;
    const int nTiles = N >> 7;
    const int mt = blockIdx.x / nTiles;
    const int nt = blockIdx.x - mt * nTiles;
    const int m0 = mt << 7, n0 = nt << 7;

    const int lane = tid & 63;
    const int wv   = tid >> 6;           // 0..3
    const int wr   = (wv >> 1) << 6;     // wave row offset: 0 or 64
    const int wc   = (wv & 1) << 6;      // wave col offset: 0 or 64
    const int fr   = lane & 15;          // row-in-16
    const int fk   = (lane >> 4) << 3;   // k-offset in shorts (0,8,16,24)

    const int srow = tid >> 1;
    const int scg  = (tid & 1) << 4;     // 0 or 16

    const float* arow = A  + (size_t)(m0 + srow) * K + scg;
    const float* brow = Bt + (size_t)(n0 + srow) * K + scg;

    f32x4 acc[4][4] = {};

    for (int kt = 0; kt < K; kt += 32) {
        float4 av[4], bv[4];
#pragma unroll
        for (int j = 0; j < 4; ++j) {
            av[j] = *(const float4*)(arow + kt + 4 * j);
            bv[j] = *(const float4*)(brow + kt + 4 * j);
        }
        __syncthreads();
        {
            short ahl[16], bhl[16], all_[16], bll[16];
#pragma unroll
            for (int j = 0; j < 4; ++j) {
#pragma unroll
                for (int e = 0; e < 4; ++e) {
                    const float fa = (&av[j].x)[e];
                    const float fb = (&bv[j].x)[e];
                    const unsigned short ha = f2b(fa);
                    const unsigned short hb = f2b(fb);
                    ahl[j * 4 + e] = (short)ha;
                    bhl[j * 4 + e] = (short)hb;
                    if constexpr (SPLIT) {
                        all_[j * 4 + e] = (short)f2b(fa - b2f(ha));
                        bll[j * 4 + e] = (short)f2b(fb - b2f(hb));
                    }
                }
            }
            const int sb = srow * 40 + scg;
            *(bf16x8*)&Ah[sb]     = *(bf16x8*)&ahl[0];
            *(bf16x8*)&Ah[sb + 8] = *(bf16x8*)&ahl[8];
            *(bf16x8*)&Bh[sb]     = *(bf16x8*)&bhl[0];
            *(bf16x8*)&Bh[sb + 8] = *(bf16x8*)&bhl[8];
            if constexpr (SPLIT) {
                *(bf16x8*)&Al[sb]     = *(bf16x8*)&all_[0];
                *(bf16x8*)&Al[sb + 8] = *(bf16x8*)&all_[8];
                *(bf16x8*)&Bl[sb]     = *(bf16x8*)&bll[0];
                *(bf16x8*)&Bl[sb + 8] = *(bf16x8*)&bll[8];
            }
        }
        __syncthreads();
        bf16x8 ah[4], bh_[4], al[4], bl[4];
#pragma unroll
        for (int i = 0; i < 4; ++i) {
            ah[i]  = *(const bf16x8*)&Ah[(wr + i * 16 + fr) * 40 + fk];
            bh_[i] = *(const bf16x8*)&Bh[(wc + i * 16 + fr) * 40 + fk];
            if constexpr (SPLIT) {
                al[i] = *(const bf16x8*)&Al[(wr + i * 16 + fr) * 40 + fk];
                bl[i] = *(const bf16x8*)&Bl[(wc + i * 16 + fr) * 40 + fk];
            }
        }
#pragma unroll
        for (int mi = 0; mi < 4; ++mi) {
#pragma unroll
            for (int ni = 0; ni < 4; ++ni) {
                acc[mi][ni] = __builtin_amdgcn_mfma_f32_16x16x32_bf16(
                                  ah[mi], bh_[ni], acc[mi][ni], 0, 0, 0);
                if constexpr (SPLIT) {
                    acc[mi][ni] = __builtin_amdgcn_mfma_f32_16x16x32_bf16(
                                      ah[mi], bl[ni], acc[mi][ni], 0, 0, 0);
                    acc[mi][ni] = __builtin_amdgcn_mfma_f32_16x16x32_bf16(
                                      al[mi], bh_[ni], acc[mi][ni], 0, 0, 0);
                }
            }
        }
    }

    float bsv[4];
#pragma unroll
    for (int ni = 0; ni < 4; ++ni) {
        const int col = n0 + wc + ni * 16 + fr;
        bsv[ni] = bias1[col] + (bias2 ? bias2[col] : 0.0f);
    }
#pragma unroll
    for (int mi = 0; mi < 4; ++mi) {
#pragma unroll
        for (int i = 0; i < 4; ++i) {
            const int m = m0 + wr + mi * 16 + ((lane >> 4) << 2) + i;
            float* crow = C + (size_t)m * N;
#pragma unroll
            for (int ni = 0; ni < 4; ++ni) {
                const int col = n0 + wc + ni * 16 + fr;
                crow[col] = acc[mi][ni][i] + bsv[ni];
            }
        }
    }
}

// ---------------------------------------------------------------- recurrence
// 128 blocks x 512 threads. team = bid&15, wg = bid>>4 (0..7), 128 W_h rows/wg.
// Exchange: word pair for row r of wg j at slab[j*256 + 2*(r-128j) + {0,1}]:
// lo = [hb0 hb1 hb2 | tag16], hi = [hb3 | tag16]; tag = step of the h carried.
// Slab: ull hx[2][16 team][8 wg][256] = 512 KB of d_ws. 2-slab ping-pong;
// 0xAA ws poison -> tag 0xAAAA matches no step.
//
// Dense poll map: remote word id w in [0,1792): wr=w>>8, ww=w&255,
// wi=wr+(wr>=wg) (skip self), slab word = wi*256+ww, row = wi*128+(ww>>1),
// half = ww&1. Thread tid polls w = tid+512k, k=0..3 (w3 invalid for
// tid>=256 -> dummy: alias w0, dn[3] pre-set, never scattered).
__global__ __launch_bounds__(512, 1) void rnn_kernel(float* __restrict__ Xhs, // [64][512][1024]
                                                     const float* __restrict__ h0,
                                                     const float* __restrict__ Wh,
                                                     ull* __restrict__ hx)
{
    __shared__ short hlA[2][32 * 128];   // double-buffered fragment-major h (16 KB)

    const int tid  = threadIdx.x;
    const int bid  = blockIdx.x;
    const int team = bid & 15;
    const int wg   = bid >> 4;       // 0..7
    const int r0   = wg << 7;        // 128 W_h rows
    const int b0   = team << 2;      // 4 batch rows

    const int lane = tid & 63;
    const int wv   = tid >> 6;       // 0..7

    // ---- one-time: 128-row W slice -> register-resident bf16 B-fragments
    bf16x8 wfrag[32];
    {
        const float* wrow = Wh + (size_t)(r0 + wv * 16 + (lane & 15)) * Hh + ((lane >> 4) << 3);
#pragma unroll
        for (int s = 0; s < 32; ++s) {
            const float4 lo = *(const float4*)(wrow + s * 32);
            const float4 hi = *(const float4*)(wrow + s * 32 + 4);
            bf16x8 w;
            w[0] = (short)f2b(lo.x); w[1] = (short)f2b(lo.y);
            w[2] = (short)f2b(lo.z); w[3] = (short)f2b(lo.w);
            w[4] = (short)f2b(hi.x); w[5] = (short)f2b(hi.y);
            w[6] = (short)f2b(hi.z); w[7] = (short)f2b(hi.w);
            wfrag[s] = w;
        }
    }

    // ---- one-time: h0 -> hlA[0] (bf16, fragment-major)
#pragma unroll
    for (int it = 0; it < 2; ++it) {
        const int idx = it * 512 + tid;   // 1024 float4 chunks of [4][1024]
        const int b   = idx >> 8;
        const int k0  = (idx & 255) << 2;
        const float4 v = *(const float4*)&h0[(size_t)(b0 + b) * Hh + k0];
        *(ull*)&hlA[0][hla_addr(k0, b)] = pack4(v.x, v.y, v.z, v.w);
    }

    // ---- per-thread dense poll assignment (4 words, w3 may be dummy)
    int  soffA[4], baseA[4];
    bool halfA[4];
    const bool dm3 = (tid >= 256);     // word 3 invalid -> dummy
#pragma unroll
    for (int j = 0; j < 4; ++j) {
        int w = tid + j * 512;
        if (w >= 1792) w = tid;        // dummy: alias word 0 (never scattered)
        const int wr = w >> 8;
        const int ww = w & 255;
        const int wi = wr + ((wr >= wg) ? 1 : 0);   // skip self
        soffA[j] = (wi << 8) + ww;
        baseA[j] = hla_base((wi << 7) + (ww >> 1));
        halfA[j] = (ww & 1) != 0;
    }

    // ---- extraction-lane state: lane<16 owns (batch i=0..3, row exrow)
    const bool ex    = (lane < 16);
    const int  exrow = r0 + wv * 16 + lane;
    const int  sb    = hla_base(exrow);
    float hprev[4] = {0.f, 0.f, 0.f, 0.f};
    if (ex) {
#pragma unroll
        for (int i = 0; i < 4; ++i)
            hprev[i] = h0[(size_t)(b0 + i) * Hh + exrow];
    }
    __syncthreads();

    const int aoff = (lane & 3) * 32 + ((lane >> 4) << 3);   // shorts

    for (int t = 0; t < Tt; ++t) {
        const short* hc = hlA[t & 1];
        short*       hn = hlA[(t + 1) & 1];

        // ---- x(t) load issued first: hides under the MFMA block
        float xr[4] = {0.f, 0.f, 0.f, 0.f};
        if (ex) {
#pragma unroll
            for (int i = 0; i < 4; ++i)
                xr[i] = Xhs[((size_t)(b0 + i) * Tt + t) * Hh + exrow];
        }

        // ---- pre = h(t) @ W^T : 32 MFMAs in 4 independent chains
        f32x4 acc0 = {0.f, 0.f, 0.f, 0.f}, acc1 = acc0, acc2 = acc0, acc3 = acc0;
#pragma unroll
        for (int s = 0; s < 32; s += 4) {
            acc0 = __builtin_amdgcn_mfma_f32_16x16x32_bf16(
                       *(const bf16x8*)(hc + (s + 0) * 128 + aoff), wfrag[s + 0], acc0, 0, 0, 0);
            acc1 = __builtin_amdgcn_mfma_f32_16x16x32_bf16(
                       *(const bf16x8*)(hc + (s + 1) * 128 + aoff), wfrag[s + 1], acc1, 0, 0, 0);
            acc2 = __builtin_amdgcn_mfma_f32_16x16x32_bf16(
                       *(const bf16x8*)(hc + (s + 2) * 128 + aoff), wfrag[s + 2], acc2, 0, 0, 0);
            acc3 = __builtin_amdgcn_mfma_f32_16x16x32_bf16(
                       *(const bf16x8*)(hc + (s + 3) * 128 + aoff), wfrag[s + 3], acc3, 0, 0, 0);
        }
        const f32x4 accs01 = acc0 + acc1;
        const f32x4 accs23 = acc2 + acc3;
        const f32x4 acc    = accs01 + accs23;

        // ---- extract h(t+1) for owned (batch, row)
        float hnew[4] = {0.f, 0.f, 0.f, 0.f};
        unsigned short hb[4] = {0, 0, 0, 0};
        if (ex) {
#pragma unroll
            for (int i = 0; i < 4; ++i) {
                const float pre = acc[i] + xr[i];
                hnew[i]  = 0.5f * fmaxf(pre, 0.0f) + 0.5f * hprev[i];
                hprev[i] = hnew[i];
                hb[i]    = f2b(hnew[i]);
            }
        }

        if (t + 1 < Tt) {
            ull* __restrict__ slab =
                hx + (size_t)(((t + 1) & 1) * 16 + team) * (8 * 256);
            const unsigned want = (unsigned)(t + 1);

            // ---- publish straight from registers (critical path), then
            //      self-inject into next buffer
            if (ex) {
                const ull tg = (ull)want << 48;
                const ull wlo = (ull)hb[0] | ((ull)hb[1] << 16)
                              | ((ull)hb[2] << 32) | tg;
                const ull whi = (ull)hb[3] | tg;
                const int pw = (wg << 8) + ((wv * 16 + lane) << 1);
                __hip_atomic_store(&slab[pw],     wlo,
                                   __ATOMIC_RELAXED, __HIP_MEMORY_SCOPE_AGENT);
                __hip_atomic_store(&slab[pw + 1], whi,
                                   __ATOMIC_RELAXED, __HIP_MEMORY_SCOPE_AGENT);
                hn[sb]      = (short)hb[0];
                hn[sb + 32] = (short)hb[1];
                hn[sb + 64] = (short)hb[2];
                hn[sb + 96] = (short)hb[3];
            }

            // ---- poll remote words: 2-deep pipelined sampling (A/B ping-
            // pong over the same addresses, all compiler-visible atomics).
            // Checking A while B's loads are outstanding -> compiler emits
            // counted vmcnt -> each word sampled every ~L/2 cycles.
            {
                ull a[4], b[4];
                bool dn[4] = {false, false, false, dm3};
#pragma unroll
                for (int j = 0; j < 4; ++j)
                    a[j] = __hip_atomic_load(&slab[soffA[j]], __ATOMIC_RELAXED,
                                             __HIP_MEMORY_SCOPE_AGENT);
#pragma unroll
                for (int j = 0; j < 4; ++j)
                    b[j] = __hip_atomic_load(&slab[soffA[j]], __ATOMIC_RELAXED,
                                             __HIP_MEMORY_SCOPE_AGENT);
                int rem = dm3 ? 3 : 4;
                while (rem > 0) {
                    // check batch A (B outstanding)
#pragma unroll
                    for (int j = 0; j < 4; ++j) {
                        if (!dn[j] && (unsigned)(a[j] >> 48) == want) {
                            dn[j] = true; --rem;
                            const int bs = baseA[j];
                            if (!halfA[j]) {
                                hn[bs]      = (short)(a[j] & 0xffffu);
                                hn[bs + 32] = (short)((a[j] >> 16) & 0xffffu);
                                hn[bs + 64] = (short)((a[j] >> 32) & 0xffffu);
                            } else {
                                hn[bs + 96] = (short)(a[j] & 0xffffu);
                            }
                        }
                    }
                    if (rem <= 0) break;
#pragma unroll
                    for (int j = 0; j < 4; ++j)
                        a[j] = __hip_atomic_load(&slab[soffA[j]], __ATOMIC_RELAXED,
                                                 __HIP_MEMORY_SCOPE_AGENT);
                    // check batch B (A outstanding)
#pragma unroll
                    for (int j = 0; j < 4; ++j) {
                        if (!dn[j] && (unsigned)(b[j] >> 48) == want) {
                            dn[j] = true; --rem;
                            const int bs = baseA[j];
                            if (!halfA[j]) {
                                hn[bs]      = (short)(b[j] & 0xffffu);
                                hn[bs + 32] = (short)((b[j] >> 16) & 0xffffu);
                                hn[bs + 64] = (short)((b[j] >> 32) & 0xffffu);
                            } else {
                                hn[bs + 96] = (short)(b[j] & 0xffffu);
                            }
                        }
                    }
                    if (rem <= 0) break;
#pragma unroll
                    for (int j = 0; j < 4; ++j)
                        b[j] = __hip_atomic_load(&slab[soffA[j]], __ATOMIC_RELAXED,
                                                 __HIP_MEMORY_SCOPE_AGENT);
                }
            }

            // ---- hs output store after poll: hides under the barrier
            if (ex) {
#pragma unroll
                for (int i = 0; i < 4; ++i)
                    Xhs[((size_t)(b0 + i) * Tt + t) * Hh + exrow] = hnew[i];
            }
            __syncthreads();   // hn complete -> becomes hc of step t+1
        } else {
            // last step: just emit hs
            if (ex) {
#pragma unroll
                for (int i = 0; i < 4; ++i)
                    Xhs[((size_t)(b0 + i) * Tt + t) * Hh + exrow] = hnew[i];
            }
        }
    }
}

// ---------------------------------------------------------------- launch
extern "C" void kernel_launch(void* const* d_in, const int* in_sizes, int n_in,
                              void* d_out, int out_size, void* d_ws, size_t ws_size,
                              hipStream_t stream)
{
    (void)in_sizes; (void)n_in; (void)out_size; (void)ws_size;

    const float* obs  = (const float*)d_in[0];  // [64][512][256]
    const float* h0   = (const float*)d_in[1];  // [64][1024]
    const float* Win  = (const float*)d_in[2];  // [1024][256]
    const float* bin  = (const float*)d_in[3];  // [1024]
    const float* Wh   = (const float*)d_in[4];  // [1024][1024]
    const float* bh   = (const float*)d_in[5];  // [1024]
    const float* Wout = (const float*)d_in[6];  // [256][1024]
    const float* bout = (const float*)d_in[7];  // [256]

    float* outs = (float*)d_out;                   // [64][512][256]
    float* hs   = outs + (size_t)Bb * Tt * Oo;     // [64][512][1024] (doubles as X)

    ull* hx = (ull*)d_ws;                          // [2][16][8][256] x 8 B = 512 KB

    // Phase A: X = obs @ W_in^T + b_in + b_h  -> hs region (split-bf16 MFMA)
    gemm_mfma_bt<1><<<(Bb * Tt / 128) * (Hh / 128), 256, 0, stream>>>(
        obs, Win, bin, bh, hs, Bb * Tt, Hh, Dd);

    // Phase B: sequential recurrence (in-place X -> hs).
    rnn_kernel<<<128, 512, 0, stream>>>(hs, h0, Wh, hx);

    // Phase C: outs = hs @ W_out^T + b_out (plain bf16 MFMA)
    gemm_mfma_bt<0><<<(Bb * Tt / 128) * (Oo / 128), 256, 0, stream>>>(
        hs, Wout, bout, nullptr, outs, Bb * Tt, Oo, Hh);
}